// Round 11
// baseline (252.397 us; speedup 1.0000x reference)
//
#include <hip/hip_runtime.h>

// B=8, N=2048, DIN=DOUT=128, DA=2, NEG_SLOPE=0.2
// out[b,i,:] = sum_j mask[b,i,j]*w[b,j]*xv[b,j,:] / sum_j mask[b,i,j]*w[b,j]
//   w[b,j]  = exp( leaky(x@Wc[0])*Wcat[2] + leaky(x@Wc[1])*Wcat[3] )  (lr_row cancels)
//   xv      = x @ Wx^T + bx
// u: 9 B-fragment tiles per 32-k t-step (verified R7/R10; tile8 col0 = w).
// Abuf: mask as bf16 {1,0} in exact mfma A-fragment order (verified R10).

typedef __bf16 bf16x8 __attribute__((ext_vector_type(8)));
typedef float  f32x4  __attribute__((ext_vector_type(4)));
typedef int    i32x4  __attribute__((ext_vector_type(4)));
typedef unsigned int u32;

#define MFMA_BF16(a, b, c) __builtin_amdgcn_mfma_f32_16x16x32_bf16((a), (b), (c), 0, 0, 0)

static __device__ __forceinline__ bf16x8 cvt8(f32x4 a, f32x4 b) {
  bf16x8 r;
  r[0] = (__bf16)a[0]; r[1] = (__bf16)a[1]; r[2] = (__bf16)a[2]; r[3] = (__bf16)a[3];
  r[4] = (__bf16)b[0]; r[5] = (__bf16)b[1]; r[6] = (__bf16)b[2]; r[7] = (__bf16)b[3];
  return r;
}

// ---------------------------------------------------------------------------
// Kernel A (verified R6-R10, unchanged): w[k], xv[k][c] -> u, 9 tiles/t-step:
//   n<8: elem(b,t,n,lane,j) = w[k]*xv[k][n*16+np],  k = t*32+(lane>>4)*8+j
//   n=8: elem = (np==0) ? w[k] : 0    (denominator column)
// flat index (((b*64+t)*9+n)*64+lane)*8+j
// ---------------------------------------------------------------------------
__global__ __launch_bounds__(256) void prep_kernel(
    const float* __restrict__ x, const float* __restrict__ Wc,
    const float* __restrict__ Wcat, const float* __restrict__ Wx,
    const float* __restrict__ bx, __bf16* __restrict__ u)
{
  __shared__ __bf16 lds[9216];
  const int blk = blockIdx.x;
  const int b = blk >> 5, mt = blk & 31;
  const int wv = threadIdx.x >> 6, lane = threadIdx.x & 63;
  const int np = lane & 15, G = lane >> 4;
  const int r0 = mt * 64 + wv * 16;

  const float* xp = x + ((size_t)(b * 2048 + r0 + np)) * 128 + G * 8;
  bf16x8 af[4];
#pragma unroll
  for (int kk = 0; kk < 4; ++kk) {
    f32x4 x0 = *(const f32x4*)(xp + kk * 32);
    f32x4 x1 = *(const f32x4*)(xp + kk * 32 + 4);
    af[kk] = cvt8(x0, x1);
  }

  f32x4 acc[8], accC;
#pragma unroll
  for (int n = 0; n < 8; ++n) { acc[n][0] = 0.f; acc[n][1] = 0.f; acc[n][2] = 0.f; acc[n][3] = 0.f; }
  accC[0] = accC[1] = accC[2] = accC[3] = 0.f;

#pragma unroll
  for (int n = 0; n < 8; ++n) {
    const float* wp = Wx + (n * 16 + np) * 128 + G * 8;
#pragma unroll
    for (int kk = 0; kk < 4; ++kk) {
      f32x4 w0 = *(const f32x4*)(wp + kk * 32);
      f32x4 w1 = *(const f32x4*)(wp + kk * 32 + 4);
      acc[n] = MFMA_BF16(af[kk], cvt8(w0, w1), acc[n]);
    }
  }
#pragma unroll
  for (int kk = 0; kk < 4; ++kk) {
    bf16x8 bf;
    if (np < 2) {
      const float* cp = Wc + np * 128 + kk * 32 + G * 8;
      f32x4 c0 = *(const f32x4*)cp;
      f32x4 c1 = *(const f32x4*)(cp + 4);
      bf = cvt8(c0, c1);
    } else {
#pragma unroll
      for (int j = 0; j < 8; ++j) bf[j] = (__bf16)0.0f;
    }
    accC = MFMA_BF16(af[kk], bf, accC);
  }

  const float a20 = Wcat[2], a21 = Wcat[3];
  float wexp[4];
#pragma unroll
  for (int r = 0; r < 4; ++r) {
    float c0 = __shfl(accC[r], lane & 48);
    float c1 = __shfl(accC[r], (lane & 48) | 1);
    c0 = c0 > 0.f ? c0 : 0.2f * c0;
    c1 = c1 > 0.f ? c1 : 0.2f * c1;
    wexp[r] = __expf(c0 * a20 + c1 * a21);
  }

  const int t_rel = wv >> 1;
  const int g_store = (wv & 1) * 2 + (G >> 1);
  const int j0 = (G & 1) * 4;
#pragma unroll
  for (int n = 0; n < 8; ++n) {
    float bxv = bx[n * 16 + np];
#pragma unroll
    for (int r = 0; r < 4; ++r)
      lds[(t_rel * 9 + n) * 512 + g_store * 128 + np * 8 + j0 + r] =
          (__bf16)(wexp[r] * (acc[n][r] + bxv));
  }
  {
#pragma unroll
    for (int r = 0; r < 4; ++r)
      lds[(t_rel * 9 + 8) * 512 + g_store * 128 + np * 8 + j0 + r] =
          (np == 0) ? (__bf16)wexp[r] : (__bf16)0.0f;
  }
  __syncthreads();
  __bf16* dst = u + ((size_t)(b * 64 + mt * 2)) * 9 * 512;
  for (int s = threadIdx.x; s < 1152; s += 256)
    ((i32x4*)dst)[s] = ((const i32x4*)lds)[s];
}

// ---------------------------------------------------------------------------
// Kernel P (verified R10, unchanged): mask -> bf16 {1,0} in A-frag order.
// Flat: Abuf[ (((b*64+rt)*64 + t)*2 + mi)*512 + l*8 + j ]
// ---------------------------------------------------------------------------
__global__ __launch_bounds__(256) void packA_kernel(
    const int* __restrict__ mask, __bf16* __restrict__ Abuf)
{
  __shared__ int sm[32 * 129];
  const int b = blockIdx.x & 7, rt = blockIdx.x >> 3;
  const int tid = threadIdx.x;
  const int* mbase = mask + ((size_t)b * 2048 + rt * 32) * 2048;
  __bf16* obase = Abuf + (size_t)(b * 64 + rt) * 64 * 1024;

  const int row_r = tid >> 3;
  const int cb8 = (tid & 7) * 16;
  const int f = tid >> 5;
  const int tk = f >> 1, mi = f & 1;

  for (int ch = 0; ch < 16; ++ch) {
    const int* rp = mbase + (size_t)row_r * 2048 + ch * 128 + cb8;
    i32x4 v0 = *(const i32x4*)rp;
    i32x4 v1 = *(const i32x4*)(rp + 4);
    i32x4 v2 = *(const i32x4*)(rp + 8);
    i32x4 v3 = *(const i32x4*)(rp + 12);
    __syncthreads();
    *(i32x4*)&sm[row_r * 129 + cb8 + 0]  = v0;
    *(i32x4*)&sm[row_r * 129 + cb8 + 4]  = v1;
    *(i32x4*)&sm[row_r * 129 + cb8 + 8]  = v2;
    *(i32x4*)&sm[row_r * 129 + cb8 + 12] = v3;
    __syncthreads();
#pragma unroll
    for (int h = 0; h < 2; ++h) {
      const int l = (tid & 31) + h * 32;
      const int row = mi * 16 + (l & 15);
      const int col = tk * 32 + (l >> 4) * 8;
      u32 P[4];
#pragma unroll
      for (int q = 0; q < 4; ++q) {
        u32 lo = sm[row * 129 + col + 2 * q]     ? 0x3F80u : 0u;
        u32 hi = sm[row * 129 + col + 2 * q + 1] ? 0x3F800000u : 0u;
        P[q] = lo | hi;
      }
      __bf16* op = obase + ((size_t)(ch * 4 + tk) * 2 + mi) * 512 + l * 8;
      *(i32x4*)op = *(const i32x4*)P;
    }
  }
}

// ---------------------------------------------------------------------------
// Kernel B v11: barrier-free, LDS-free, VALU-free register MFMA loop.
// Every prior variant was either barrier-locked at 2 blocks/CU (v6-v10) or a
// fat reg-step (11+ loads, v1-v5). Now a step is 5x16B loads + 6 MFMA, zero
// unpack. 2-deep named-buffer pipeline, consume-then-refill (R4 lesson).
// Block = 32 rows x 128 cols, 4 waves (wave = 2 m-frags x 2 n-tiles + den).
// 512 blocks, 2048 waves, ~8 waves/CU; worst-case full serialization of a
// step = 5 loads x ~250cy L2 / 2 waves/SIMD ~ 16 us; sane scheduling ~12.
// ---------------------------------------------------------------------------
__global__ __launch_bounds__(256) void attn_kernel(
    const __bf16* __restrict__ Abuf, const __bf16* __restrict__ u,
    float* __restrict__ out)
{
  const int b = blockIdx.x & 7, rt = blockIdx.x >> 3;  // 8 x 64 (batch->XCD)
  const int wv = threadIdx.x >> 6, lane = threadIdx.x & 63;
  const int np = lane & 15, G = lane >> 4;
  const int row0 = rt * 32;
  const int n0 = wv * 2, n1 = n0 + 1;

  const char* gA = (const char*)Abuf + (size_t)(b * 64 + rt) * 64 * 2048 + lane * 16;
  const char* gu = (const char*)u + (size_t)b * 64 * 9216 + lane * 16;

  f32x4 acc[2][3];  // [mi][n0, n1, den]
#pragma unroll
  for (int mi = 0; mi < 2; ++mi)
#pragma unroll
    for (int n = 0; n < 3; ++n) { acc[mi][n][0] = 0.f; acc[mi][n][1] = 0.f; acc[mi][n][2] = 0.f; acc[mi][n][3] = 0.f; }

  bf16x8 A0X, A1X, U0X, U1X, UDX;   // buffer X
  bf16x8 A0Y, A1Y, U0Y, U1Y, UDY;   // buffer Y

#define LOADF(S, t)                                                      \
  do {                                                                   \
    const char* ga_ = gA + (size_t)(t) * 2048;                           \
    const char* gu_ = gu + (size_t)(t) * 9216;                           \
    A0##S = *(const bf16x8*)(ga_);                                       \
    A1##S = *(const bf16x8*)(ga_ + 1024);                                \
    U0##S = *(const bf16x8*)(gu_ + n0 * 1024);                           \
    U1##S = *(const bf16x8*)(gu_ + n1 * 1024);                           \
    UD##S = *(const bf16x8*)(gu_ + 8 * 1024);                            \
  } while (0)

#define COMPF(S)                                                         \
  do {                                                                   \
    acc[0][0] = MFMA_BF16(A0##S, U0##S, acc[0][0]);                      \
    acc[0][1] = MFMA_BF16(A0##S, U1##S, acc[0][1]);                      \
    acc[0][2] = MFMA_BF16(A0##S, UD##S, acc[0][2]);                      \
    acc[1][0] = MFMA_BF16(A1##S, U0##S, acc[1][0]);                      \
    acc[1][1] = MFMA_BF16(A1##S, U1##S, acc[1][1]);                      \
    acc[1][2] = MFMA_BF16(A1##S, UD##S, acc[1][2]);                      \
  } while (0)

  LOADF(X, 0);
  LOADF(Y, 1);
  for (int t = 0; t < 62; t += 2) {
    COMPF(X); LOADF(X, t + 2);   // consume THEN refill (R4 lesson)
    COMPF(Y); LOADF(Y, t + 3);
  }
  COMPF(X);
  COMPF(Y);
#undef LOADF
#undef COMPF

  // epilogue (verified R1-R10): D row = mi*16+4G+r, col = n*16+np;
  // den = col 0 of tile-8 output, broadcast from lane (lane&48).
#pragma unroll
  for (int mi = 0; mi < 2; ++mi) {
#pragma unroll
    for (int r = 0; r < 4; ++r) {
      float den = __shfl(acc[mi][2][r], lane & 48);
      float inv = 1.0f / den;
      float* op = out + ((size_t)b * 2048 + row0 + mi * 16 + 4 * G + r) * 128 + np;
      op[n0 * 16] = acc[mi][0][r] * inv;
      op[n1 * 16] = acc[mi][1][r] * inv;
    }
  }
}

extern "C" void kernel_launch(void* const* d_in, const int* in_sizes, int n_in,
                              void* d_out, int out_size, void* d_ws, size_t ws_size,
                              hipStream_t stream) {
  const float* x    = (const float*)d_in[0];
  const int*   mask = (const int*)d_in[1];
  // d_in[2] = Wr : unused (lr_row cancels in softmax over j)
  const float* Wc   = (const float*)d_in[3];
  const float* Wcat = (const float*)d_in[4];
  const float* Wx   = (const float*)d_in[5];
  const float* bx   = (const float*)d_in[6];
  float* out = (float*)d_out;

  // workspace: u 4.72 MB | Abuf 67.1 MB
  const size_t U_BYTES = (size_t)8 * 64 * 9 * 512 * 2;
  const size_t A_BYTES = (size_t)8 * 2048 * 2048 * 2;
  if (ws_size < U_BYTES + A_BYTES) return;
  __bf16* u    = (__bf16*)d_ws;
  __bf16* Abuf = (__bf16*)((char*)d_ws + U_BYTES);

  prep_kernel<<<256, 256, 0, stream>>>(x, Wc, Wcat, Wx, bx, u);
  packA_kernel<<<512, 256, 0, stream>>>(mask, Abuf);
  attn_kernel<<<512, 256, 0, stream>>>(Abuf, u, out);
}